// Round 4
// baseline (219.221 us; speedup 1.0000x reference)
//
#include <hip/hip_runtime.h>
#include <hip/hip_fp16.h>

typedef _Float16 half8 __attribute__((ext_vector_type(8)));
typedef _Float16 half4 __attribute__((ext_vector_type(4)));
typedef _Float16 half2v __attribute__((ext_vector_type(2)));
typedef float f32x4 __attribute__((ext_vector_type(4)));

#define SEQ   2048
#define DM    1024
#define NH    16
#define HD    64
#define BSZ   4

#if __has_builtin(__builtin_amdgcn_exp2f)
#define EXP2(x) __builtin_amdgcn_exp2f(x)
#else
#define EXP2(x) exp2f(x)
#endif

// Q pre-scale: (1/sqrt(64)) * log2(e)  -> scores land in log2 domain
#define QSCALE 0.1803368801f

// async global->LDS, 16B per lane. LDS dest = wave-uniform base + lane*16.
__device__ __forceinline__ void gload16(const void* g, void* l) {
  __builtin_amdgcn_global_load_lds((const __attribute__((address_space(1))) void*)g,
                                   (__attribute__((address_space(3))) void*)l,
                                   16, 0, 0);
}

__device__ __forceinline__ f32x4 vmax4(f32x4 a, f32x4 b) {
  f32x4 r;
  r[0] = fmaxf(a[0], b[0]); r[1] = fmaxf(a[1], b[1]);
  r[2] = fmaxf(a[2], b[2]); r[3] = fmaxf(a[3], b[3]);
  return r;
}

// ---------------- fp32 -> fp16 convert (vectorized) ----------------
__global__ void cvt4(const float* __restrict__ src, _Float16* __restrict__ dst, int n4) {
  int i = blockIdx.x * blockDim.x + threadIdx.x;
  if (i < n4) {
    float4 v = ((const float4*)src)[i];
    half4 o = { (_Float16)v.x, (_Float16)v.y, (_Float16)v.z, (_Float16)v.w };
    ((half4*)dst)[i] = o;
  }
}

// ---------------- GEMM: C = A * B^T, A[M][1024] f16, B[N][1024] f16 ----------------
// 128x128 tile, 4 waves (2x2), BK=32, 16x16x32 f16 MFMA (m97 structure).
// MODE 0: QKV projection epilogue -> Q(scaled by QSCALE)[bh][s][64], K[bh][s][64],
//         Vt[bh][64][s] (f16)
// MODE 1: plain f32 store to out[M][1024]
template<int MODE>
__global__ __launch_bounds__(256)
void gemm_hk(const _Float16* __restrict__ A, const _Float16* __restrict__ B,
             _Float16* __restrict__ oQ, _Float16* __restrict__ oK,
             _Float16* __restrict__ oVt, float* __restrict__ oF) {
  __shared__ _Float16 As[128*32];
  __shared__ _Float16 Bs[128*32];
  const int tid  = threadIdx.x;
  const int wid  = tid >> 6, lane = tid & 63;
  const int wm   = wid >> 1, wn = wid & 1;
  const int fr   = lane & 15, fg = lane >> 4;
  const long m0  = (long)blockIdx.x * 128;
  const long n0  = (long)blockIdx.y * 128;
  const int lrow = lane >> 2;            // 16 rows per instr (4 lanes/row)
  const int lcol = (lane & 3) * 8;       // halfs
  const _Float16* ga0 = A + (m0 + wid*32 + lrow) * 1024 + lcol;
  const _Float16* gb0 = B + (n0 + wid*32 + lrow) * 1024 + lcol;
  _Float16* lA = &As[wid*32*32];
  _Float16* lB = &Bs[wid*32*32];

  f32x4 acc[4][4] = {};

  for (int k0 = 0; k0 < 1024; k0 += 32) {
    gload16(ga0 + k0,             lA);
    gload16(ga0 + k0 + 16*1024,   lA + 16*32);
    gload16(gb0 + k0,             lB);
    gload16(gb0 + k0 + 16*1024,   lB + 16*32);
    __syncthreads();
    half8 af[4], bf[4];
#pragma unroll
    for (int i = 0; i < 4; ++i) {
      af[i] = *(const half8*)&As[(wm*64 + i*16 + fr)*32 + fg*8];
      bf[i] = *(const half8*)&Bs[(wn*64 + i*16 + fr)*32 + fg*8];
    }
#pragma unroll
    for (int i = 0; i < 4; ++i)
#pragma unroll
      for (int j = 0; j < 4; ++j)
        acc[i][j] = __builtin_amdgcn_mfma_f32_16x16x32_f16(af[i], bf[j], acc[i][j], 0, 0, 0);
    __syncthreads();
  }

  if (MODE == 0) {
    const int which = (int)(n0 >> 10);               // 0=Q 1=K 2=V (tiles never straddle)
    const int nloc0 = ((int)n0 & 1023) + wn*64;
#pragma unroll
    for (int i = 0; i < 4; ++i) {
      const long r0 = m0 + wm*64 + i*16 + fg*4;
      const int  bb = (int)(r0 >> 11);
      const int  s  = (int)(r0 & 2047);
#pragma unroll
      for (int j = 0; j < 4; ++j) {
        const int nl = nloc0 + j*16 + fr;
        const int h  = nl >> 6, d = nl & 63;
        const long bh = (long)(bb*NH + h);
        if (which == 0) {
#pragma unroll
          for (int r = 0; r < 4; ++r)
            oQ[(bh*SEQ + s + r)*HD + d] = (_Float16)(acc[i][j][r] * QSCALE);
        } else if (which == 1) {
#pragma unroll
          for (int r = 0; r < 4; ++r)
            oK[(bh*SEQ + s + r)*HD + d] = (_Float16)acc[i][j][r];
        } else {
          half4 pk = { (_Float16)acc[i][j][0], (_Float16)acc[i][j][1],
                       (_Float16)acc[i][j][2], (_Float16)acc[i][j][3] };
          *(half4*)&oVt[(bh*HD + d)*SEQ + s] = pk;   // s % 4 == 0, 8B aligned
        }
      }
    }
  } else {
#pragma unroll
    for (int i = 0; i < 4; ++i) {
      const long r0 = m0 + wm*64 + i*16 + fg*4;
#pragma unroll
      for (int j = 0; j < 4; ++j) {
        const long col = n0 + wn*64 + j*16 + fr;
#pragma unroll
        for (int r = 0; r < 4; ++r)
          oF[(r0 + r)*DM + col] = acc[i][j][r];
      }
    }
  }
}

// ---------------- RoPE in place on Q and K [bh][s][64] ----------------
__global__ void rope_k(_Float16* __restrict__ Q, _Float16* __restrict__ K,
                       const int* __restrict__ tp) {
  const int t = blockIdx.x * blockDim.x + threadIdx.x;   // over SEQ*32
  const int s = t >> 5, p = t & 31;
  _Float16* base = blockIdx.z ? K : Q;
  half2v* ptr = (half2v*)(base + ((long)blockIdx.y * SEQ + s) * HD) + p;
  half2v v = *ptr;
  const float pos = (float)tp[s];
  const float inv = exp2f(-0.41524101186f * (float)p);
  const float f = pos * inv;
  float sn, cs;
  __sincosf(f, &sn, &cs);
  const float xe = (float)v[0], xo = (float)v[1];
  half2v o = { (_Float16)(xe*cs - xo*sn), (_Float16)(xo*cs + xe*sn) };
  *ptr = o;
}

// ---------------- causal flash attention (swapped-operand, log2-domain) ----------------
// grid (BH=64, 16 qtiles of 128). 4 waves x 32 q-rows (2 sets of 16). KV tiles of 64.
// S^T = mfma(K,Q): lane fr = q -> row stats LANE-LOCAL (2 shuffles per reduce).
// O^T = mfma(V,P): rescale needs no broadcast. Scores in log2 domain (Q pre-scaled
// by log2e/8) -> p = v_exp_f32 directly. Defer-max (THR=8): skip rescale when
// __all(pm <= m+8); P bounded by 256, f16 safe. K-frags hoisted across the 2 sets
// (identical addresses). P packed via cvt_pkrtz into XOR-swizzled stride-64 LDS.
// LDS = 40960 B -> 4 blocks/CU.
__global__ __launch_bounds__(256, 4)
void fattn(const _Float16* __restrict__ Q, const _Float16* __restrict__ K,
           const _Float16* __restrict__ Vt, _Float16* __restrict__ O) {
  __shared__ _Float16 Ks[2][64*64];
  __shared__ _Float16 Vs[2][64*64];
  __shared__ _Float16 Ps[4][16*64];      // per-wave, XOR-swizzled, stride 64
  const int tid = threadIdx.x, wid = tid >> 6, lane = tid & 63;
  const int fr = lane & 15, fg = lane >> 4;
  const int bh = blockIdx.x;
  const int b = bh >> 4, h = bh & 15;
  // balanced heavy-first q-tile permutation
  const int y = blockIdx.y;
  const int perm = (y < 4) ? (15 - y) : (y < 8) ? (y + 4) : (y < 12) ? (y - 4) : (15 - y);
  const int q0 = perm * 128;
  const int qw = q0 + wid * 32;          // wave covers q rows qw .. qw+31 (2 sets of 16)
  const _Float16* Qb = Q + (long)bh * SEQ * HD;
  const _Float16* Kb = K + (long)bh * SEQ * HD;
  const _Float16* Vb = Vt + (long)bh * HD * SEQ;

  half8 qf[2][2];
#pragma unroll
  for (int s = 0; s < 2; ++s) {
    qf[s][0] = *(const half8*)&Qb[(qw + s*16 + fr)*HD + fg*8];
    qf[s][1] = *(const half8*)&Qb[(qw + s*16 + fr)*HD + 32 + fg*8];
  }

  f32x4 oaccT[2][4] = {};
  float m_s[2] = { -1e30f, -1e30f }, l_s[2] = { 0.f, 0.f };

  const int srow = lane >> 3;                 // 0..7 (row within 8-row chunk)
  const int sc16 = (lane & 7) ^ srow;         // pre-swizzled source slot
  const int r1 = wid*16 + srow, r2 = r1 + 8;  // rows this wave stages

  char* Pb = (char*)&Ps[wid][0];
  const int swp = (fr & 7) << 4;              // P swizzle for this lane's q-row
  const int nt = q0/64 + 2;

  // prologue: stage tile 0 into buf 0
  gload16(Kb + (long)r1*HD + sc16*8, &Ks[0][(wid*16)*64]);
  gload16(Kb + (long)r2*HD + sc16*8, &Ks[0][(wid*16 + 8)*64]);
  gload16(Vb + (long)r1*SEQ + sc16*8, &Vs[0][(wid*16)*64]);
  gload16(Vb + (long)r2*SEQ + sc16*8, &Vs[0][(wid*16 + 8)*64]);
  __syncthreads();

  int cur = 0;
  for (int t = 0; t < nt; ++t) {
    const int kv0 = t * 64;

    // prefetch next tile (drained by end-of-tile barrier -> latency hidden)
    if (t + 1 < nt) {
      const int nkv = kv0 + 64;
      gload16(Kb + (long)(nkv + r1)*HD + sc16*8, &Ks[cur^1][(wid*16)*64]);
      gload16(Kb + (long)(nkv + r2)*HD + sc16*8, &Ks[cur^1][(wid*16 + 8)*64]);
      gload16(Vb + (long)r1*SEQ + nkv + sc16*8,  &Vs[cur^1][(wid*16)*64]);
      gload16(Vb + (long)r2*SEQ + nkv + sc16*8,  &Vs[cur^1][(wid*16 + 8)*64]);
    }

    const char* Kc = (const char*)&Ks[cur][0];
    const char* Vc = (const char*)&Vs[cur][0];

    // K-fragments: identical for both q-sets -> load once per tile
    half8 kf0[4], kf1[4];
#pragma unroll
    for (int n = 0; n < 4; ++n) {
      const int row = n*16 + fr;
      const int sw = (row & 7) << 4;
      kf0[n] = *(const half8*)(Kc + row*128 + ((fg*16) ^ sw));
      kf1[n] = *(const half8*)(Kc + row*128 + ((64 + fg*16) ^ sw));
    }

#pragma unroll
    for (int s = 0; s < 2; ++s) {
      const int qs0 = qw + s*16;              // first q-row of this set
      if (kv0 > qs0 + 15) continue;           // fully-masked set: skip
      const int qa = qs0 + fr;                // this lane's absolute q row

      // S^T = K Q^T : lane fr = q, regs hold kv = n*16 + fg*4 + r  (log2 domain)
      f32x4 sa[4];
      __builtin_amdgcn_s_setprio(1);
#pragma unroll
      for (int n = 0; n < 4; ++n) {
        f32x4 z = {0.f, 0.f, 0.f, 0.f};
        z = __builtin_amdgcn_mfma_f32_16x16x32_f16(kf0[n], qf[s][0], z, 0, 0, 0);
        sa[n] = __builtin_amdgcn_mfma_f32_16x16x32_f16(kf1[n], qf[s][1], z, 0, 0, 0);
      }
      __builtin_amdgcn_s_setprio(0);

      if (kv0 + 63 > qs0) {                   // masked region reaches this set
#pragma unroll
        for (int n = 0; n < 4; ++n) {
          const int kvb = kv0 + n*16 + fg*4;
#pragma unroll
          for (int r = 0; r < 4; ++r)
            if (kvb + r > qa) sa[n][r] = -1e30f;
        }
      }

      // row max: vector tree (v_pk_max) + 2 shuffles
      f32x4 mx = vmax4(vmax4(sa[0], sa[1]), vmax4(sa[2], sa[3]));
      float pm = fmaxf(fmaxf(mx[0], mx[1]), fmaxf(mx[2], mx[3]));
      pm = fmaxf(pm, __shfl_xor(pm, 16));
      pm = fmaxf(pm, __shfl_xor(pm, 32));

      // defer-max: skip rescale unless max grew by > 8 (log2 units)
      if (!__all(pm <= m_s[s] + 8.0f)) {
        const float mn = fmaxf(m_s[s], pm);
        const float fac = EXP2(m_s[s] - mn);
        m_s[s] = mn;
        l_s[s] *= fac;
#pragma unroll
        for (int n = 0; n < 4; ++n) oaccT[s][n] *= fac;
      }
      const float mrow = m_s[s];

#pragma unroll
      for (int n = 0; n < 4; ++n)
#pragma unroll
        for (int r = 0; r < 4; ++r)
          sa[n][r] = EXP2(sa[n][r] - mrow);

      f32x4 s4 = (sa[0] + sa[1]) + (sa[2] + sa[3]);
      float ps = (s4[0] + s4[1]) + (s4[2] + s4[3]);
      ps += __shfl_xor(ps, 16);
      ps += __shfl_xor(ps, 32);
      l_s[s] += ps;

      // P (row q=fr, kv-consecutive) -> packed cvt + b64 writes, XOR-swizzled
#pragma unroll
      for (int n = 0; n < 4; ++n) {
        half2v lo = (half2v)__builtin_amdgcn_cvt_pkrtz(sa[n][0], sa[n][1]);
        half2v hi = (half2v)__builtin_amdgcn_cvt_pkrtz(sa[n][2], sa[n][3]);
        half4 p4 = __builtin_shufflevector(lo, hi, 0, 1, 2, 3);
        *(half4*)(Pb + ((fr*128 + n*32 + fg*8) ^ swp)) = p4;
      }

      // O^T += V^T P^T : A = V^T frag (lane fr = d), B = P frag (lane fr = q)
      __builtin_amdgcn_s_setprio(1);
#pragma unroll
      for (int ks = 0; ks < 2; ++ks) {
        const half8 pf = *(const half8*)(Pb + ((fr*128 + ks*64 + fg*16) ^ swp));
#pragma unroll
        for (int nd = 0; nd < 4; ++nd) {
          const int row = nd*16 + fr;
          const int sw = (row & 7) << 4;
          const half8 vf = *(const half8*)(Vc + row*128 + ((ks*64 + fg*16) ^ sw));
          oaccT[s][nd] = __builtin_amdgcn_mfma_f32_16x16x32_f16(vf, pf, oaccT[s][nd], 0, 0, 0);
        }
      }
      __builtin_amdgcn_s_setprio(0);
    }

    __syncthreads();           // implicit vmcnt(0): prefetch drained; buffers swappable
    cur ^= 1;
  }

  // epilogue: O^T lane fr = q -> row-contiguous packed stores
#pragma unroll
  for (int s = 0; s < 2; ++s) {
    const float rl = __builtin_amdgcn_rcpf(l_s[s]);
    _Float16* orow = O + ((long)b*SEQ + (qw + s*16 + fr))*DM + h*64;
#pragma unroll
    for (int nd = 0; nd < 4; ++nd) {
      half2v lo = (half2v)__builtin_amdgcn_cvt_pkrtz(oaccT[s][nd][0]*rl, oaccT[s][nd][1]*rl);
      half2v hi = (half2v)__builtin_amdgcn_cvt_pkrtz(oaccT[s][nd][2]*rl, oaccT[s][nd][3]*rl);
      half4 o4 = __builtin_shufflevector(lo, hi, 0, 1, 2, 3);
      *(half4*)&orow[nd*16 + fg*4] = o4;
    }
  }
}

extern "C" void kernel_launch(void* const* d_in, const int* in_sizes, int n_in,
                              void* d_out, int out_size, void* d_ws, size_t ws_size,
                              hipStream_t stream) {
  const float* x  = (const float*)d_in[0];
  const float* Wq = (const float*)d_in[1];
  const float* Wk = (const float*)d_in[2];
  const float* Wv = (const float*)d_in[3];
  const float* Wo = (const float*)d_in[4];
  const int*   tp = (const int*)d_in[5];
  float* out = (float*)d_out;

  char* ws = (char*)d_ws;
  _Float16* xh   = (_Float16*)(ws);                  // 16 MB  [8192][1024]
  _Float16* Wqkv = (_Float16*)(ws + (16u << 20));    //  6 MB  [3072][1024]
  _Float16* Woh  = (_Float16*)(ws + (22u << 20));    //  2 MB  [1024][1024]
  _Float16* Qb   = (_Float16*)(ws + (24u << 20));    // 16 MB  [64][2048][64]
  _Float16* Kb   = (_Float16*)(ws + (40u << 20));    // 16 MB
  _Float16* Vtb  = (_Float16*)(ws + (56u << 20));    // 16 MB  [64][64][2048]
  _Float16* attn = (_Float16*)(ws + (72u << 20));    // 16 MB  [8192][1024]

  cvt4<<<8192, 256, 0, stream>>>(x,  xh, 2097152);
  cvt4<<<1024, 256, 0, stream>>>(Wq, Wqkv,               262144);
  cvt4<<<1024, 256, 0, stream>>>(Wk, Wqkv + (1u << 20),  262144);
  cvt4<<<1024, 256, 0, stream>>>(Wv, Wqkv + (2u << 20),  262144);
  cvt4<<<1024, 256, 0, stream>>>(Wo, Woh,                262144);

  gemm_hk<0><<<dim3(64, 24), 256, 0, stream>>>(xh, Wqkv, Qb, Kb, Vtb, nullptr);
  rope_k<<<dim3(256, 64, 2), 256, 0, stream>>>(Qb, Kb, tp);
  fattn<<<dim3(64, 16), 256, 0, stream>>>(Qb, Kb, Vtb, attn);
  gemm_hk<1><<<dim3(64, 8), 256, 0, stream>>>(attn, Woh, nullptr, nullptr, nullptr, out);
}

// Round 5
// 198.472 us; speedup vs baseline: 1.1045x; 1.1045x over previous
//
#include <hip/hip_runtime.h>
#include <hip/hip_fp16.h>

typedef _Float16 half8 __attribute__((ext_vector_type(8)));
typedef _Float16 half4 __attribute__((ext_vector_type(4)));
typedef _Float16 half2v __attribute__((ext_vector_type(2)));
typedef float f32x4 __attribute__((ext_vector_type(4)));

#define SEQ   2048
#define DM    1024
#define NH    16
#define HD    64
#define BSZ   4

#if __has_builtin(__builtin_amdgcn_exp2f)
#define EXP2(x) __builtin_amdgcn_exp2f(x)
#else
#define EXP2(x) exp2f(x)
#endif

// Q pre-scale: (1/sqrt(64)) * log2(e)  -> scores land in log2 domain
#define QSCALE 0.1803368801f

// async global->LDS, 16B per lane. LDS dest = wave-uniform base + lane*16.
__device__ __forceinline__ void gload16(const void* g, void* l) {
  __builtin_amdgcn_global_load_lds((const __attribute__((address_space(1))) void*)g,
                                   (__attribute__((address_space(3))) void*)l,
                                   16, 0, 0);
}

__device__ __forceinline__ f32x4 vmax4(f32x4 a, f32x4 b) {
  f32x4 r;
  r[0] = fmaxf(a[0], b[0]); r[1] = fmaxf(a[1], b[1]);
  r[2] = fmaxf(a[2], b[2]); r[3] = fmaxf(a[3], b[3]);
  return r;
}

// ---------------- fp32 -> fp16 convert (vectorized) ----------------
__global__ void cvt4(const float* __restrict__ src, _Float16* __restrict__ dst, int n4) {
  int i = blockIdx.x * blockDim.x + threadIdx.x;
  if (i < n4) {
    float4 v = ((const float4*)src)[i];
    half4 o = { (_Float16)v.x, (_Float16)v.y, (_Float16)v.z, (_Float16)v.w };
    ((half4*)dst)[i] = o;
  }
}

// ---------------- GEMM: C = A * B^T, A[M][1024] f16, B[N][1024] f16 ----------------
// 128x128 tile, 4 waves (2x2), BK=32, 16x16x32 f16 MFMA (m97 structure).
// MODE 0: QKV projection epilogue -> Q(scaled by QSCALE)[bh][s][64], K[bh][s][64],
//         Vt[bh][64][s] (f16)
// MODE 1: plain f32 store to out[M][1024]
template<int MODE>
__global__ __launch_bounds__(256)
void gemm_hk(const _Float16* __restrict__ A, const _Float16* __restrict__ B,
             _Float16* __restrict__ oQ, _Float16* __restrict__ oK,
             _Float16* __restrict__ oVt, float* __restrict__ oF) {
  __shared__ _Float16 As[128*32];
  __shared__ _Float16 Bs[128*32];
  const int tid  = threadIdx.x;
  const int wid  = tid >> 6, lane = tid & 63;
  const int wm   = wid >> 1, wn = wid & 1;
  const int fr   = lane & 15, fg = lane >> 4;
  const long m0  = (long)blockIdx.x * 128;
  const long n0  = (long)blockIdx.y * 128;
  const int lrow = lane >> 2;            // 16 rows per instr (4 lanes/row)
  const int lcol = (lane & 3) * 8;       // halfs
  const _Float16* ga0 = A + (m0 + wid*32 + lrow) * 1024 + lcol;
  const _Float16* gb0 = B + (n0 + wid*32 + lrow) * 1024 + lcol;
  _Float16* lA = &As[wid*32*32];
  _Float16* lB = &Bs[wid*32*32];

  f32x4 acc[4][4] = {};

  for (int k0 = 0; k0 < 1024; k0 += 32) {
    gload16(ga0 + k0,             lA);
    gload16(ga0 + k0 + 16*1024,   lA + 16*32);
    gload16(gb0 + k0,             lB);
    gload16(gb0 + k0 + 16*1024,   lB + 16*32);
    __syncthreads();
    half8 af[4], bf[4];
#pragma unroll
    for (int i = 0; i < 4; ++i) {
      af[i] = *(const half8*)&As[(wm*64 + i*16 + fr)*32 + fg*8];
      bf[i] = *(const half8*)&Bs[(wn*64 + i*16 + fr)*32 + fg*8];
    }
#pragma unroll
    for (int i = 0; i < 4; ++i)
#pragma unroll
      for (int j = 0; j < 4; ++j)
        acc[i][j] = __builtin_amdgcn_mfma_f32_16x16x32_f16(af[i], bf[j], acc[i][j], 0, 0, 0);
    __syncthreads();
  }

  if (MODE == 0) {
    const int which = (int)(n0 >> 10);               // 0=Q 1=K 2=V (tiles never straddle)
    const int nloc0 = ((int)n0 & 1023) + wn*64;
#pragma unroll
    for (int i = 0; i < 4; ++i) {
      const long r0 = m0 + wm*64 + i*16 + fg*4;
      const int  bb = (int)(r0 >> 11);
      const int  s  = (int)(r0 & 2047);
#pragma unroll
      for (int j = 0; j < 4; ++j) {
        const int nl = nloc0 + j*16 + fr;
        const int h  = nl >> 6, d = nl & 63;
        const long bh = (long)(bb*NH + h);
        if (which == 0) {
#pragma unroll
          for (int r = 0; r < 4; ++r)
            oQ[(bh*SEQ + s + r)*HD + d] = (_Float16)(acc[i][j][r] * QSCALE);
        } else if (which == 1) {
#pragma unroll
          for (int r = 0; r < 4; ++r)
            oK[(bh*SEQ + s + r)*HD + d] = (_Float16)acc[i][j][r];
        } else {
          half4 pk = { (_Float16)acc[i][j][0], (_Float16)acc[i][j][1],
                       (_Float16)acc[i][j][2], (_Float16)acc[i][j][3] };
          *(half4*)&oVt[(bh*HD + d)*SEQ + s] = pk;   // s % 4 == 0, 8B aligned
        }
      }
    }
  } else {
#pragma unroll
    for (int i = 0; i < 4; ++i) {
      const long r0 = m0 + wm*64 + i*16 + fg*4;
#pragma unroll
      for (int j = 0; j < 4; ++j) {
        const long col = n0 + wn*64 + j*16 + fr;
#pragma unroll
        for (int r = 0; r < 4; ++r)
          oF[(r0 + r)*DM + col] = acc[i][j][r];
      }
    }
  }
}

// ---------------- RoPE in place on Q and K [bh][s][64] ----------------
__global__ void rope_k(_Float16* __restrict__ Q, _Float16* __restrict__ K,
                       const int* __restrict__ tp) {
  const int t = blockIdx.x * blockDim.x + threadIdx.x;   // over SEQ*32
  const int s = t >> 5, p = t & 31;
  _Float16* base = blockIdx.z ? K : Q;
  half2v* ptr = (half2v*)(base + ((long)blockIdx.y * SEQ + s) * HD) + p;
  half2v v = *ptr;
  const float pos = (float)tp[s];
  const float inv = exp2f(-0.41524101186f * (float)p);
  const float f = pos * inv;
  float sn, cs;
  __sincosf(f, &sn, &cs);
  const float xe = (float)v[0], xo = (float)v[1];
  half2v o = { (_Float16)(xe*cs - xo*sn), (_Float16)(xo*cs + xe*sn) };
  *ptr = o;
}

// ---------------- causal flash attention (swapped-operand, log2-domain) ----------------
// grid (BH=64, 16 qtiles of 128). 4 waves x 32 q-rows (2 sets of 16). KV tiles of 64.
// S^T = mfma(K,Q): lane fr = q -> row stats LANE-LOCAL (2 shuffles per reduce).
// O^T = mfma(V,P): rescale needs no broadcast. Scores in log2 domain -> exp2 direct.
// Defer-max (THR=8): skip rescale when __all(pm <= m+8); P bounded by 256, f16 safe.
// K-frags read inline per set (NO hoist: +32 VGPR caused a spill, round-3 lesson —
// WRITE_SIZE 16.4->29.7 MB scratch signature). P packed via cvt_pkrtz into
// XOR-swizzled stride-64 per-wave LDS. LDS = 40960 B -> 4 blocks/CU.
__global__ __launch_bounds__(256, 4)
void fattn(const _Float16* __restrict__ Q, const _Float16* __restrict__ K,
           const _Float16* __restrict__ Vt, _Float16* __restrict__ O) {
  __shared__ _Float16 Ks[2][64*64];
  __shared__ _Float16 Vs[2][64*64];
  __shared__ _Float16 Ps[4][16*64];      // per-wave, XOR-swizzled, stride 64
  const int tid = threadIdx.x, wid = tid >> 6, lane = tid & 63;
  const int fr = lane & 15, fg = lane >> 4;
  const int bh = blockIdx.x;
  const int b = bh >> 4, h = bh & 15;
  // balanced heavy-first q-tile permutation
  const int y = blockIdx.y;
  const int perm = (y < 4) ? (15 - y) : (y < 8) ? (y + 4) : (y < 12) ? (y - 4) : (15 - y);
  const int q0 = perm * 128;
  const int qw = q0 + wid * 32;          // wave covers q rows qw .. qw+31 (2 sets of 16)
  const _Float16* Qb = Q + (long)bh * SEQ * HD;
  const _Float16* Kb = K + (long)bh * SEQ * HD;
  const _Float16* Vb = Vt + (long)bh * HD * SEQ;

  half8 qf[2][2];
#pragma unroll
  for (int s = 0; s < 2; ++s) {
    qf[s][0] = *(const half8*)&Qb[(qw + s*16 + fr)*HD + fg*8];
    qf[s][1] = *(const half8*)&Qb[(qw + s*16 + fr)*HD + 32 + fg*8];
  }

  f32x4 oaccT[2][4] = {};
  float m_s[2] = { -1e30f, -1e30f }, l_s[2] = { 0.f, 0.f };

  const int srow = lane >> 3;                 // 0..7 (row within 8-row chunk)
  const int sc16 = (lane & 7) ^ srow;         // pre-swizzled source slot
  const int r1 = wid*16 + srow, r2 = r1 + 8;  // rows this wave stages

  char* Pb = (char*)&Ps[wid][0];
  const int swp = (fr & 7) << 4;              // P swizzle for this lane's q-row
  const int nt = q0/64 + 2;

  // prologue: stage tile 0 into buf 0
  gload16(Kb + (long)r1*HD + sc16*8, &Ks[0][(wid*16)*64]);
  gload16(Kb + (long)r2*HD + sc16*8, &Ks[0][(wid*16 + 8)*64]);
  gload16(Vb + (long)r1*SEQ + sc16*8, &Vs[0][(wid*16)*64]);
  gload16(Vb + (long)r2*SEQ + sc16*8, &Vs[0][(wid*16 + 8)*64]);
  __syncthreads();

  int cur = 0;
  for (int t = 0; t < nt; ++t) {
    const int kv0 = t * 64;

    // prefetch next tile (drained by end-of-tile barrier -> latency hidden)
    if (t + 1 < nt) {
      const int nkv = kv0 + 64;
      gload16(Kb + (long)(nkv + r1)*HD + sc16*8, &Ks[cur^1][(wid*16)*64]);
      gload16(Kb + (long)(nkv + r2)*HD + sc16*8, &Ks[cur^1][(wid*16 + 8)*64]);
      gload16(Vb + (long)r1*SEQ + nkv + sc16*8,  &Vs[cur^1][(wid*16)*64]);
      gload16(Vb + (long)r2*SEQ + nkv + sc16*8,  &Vs[cur^1][(wid*16 + 8)*64]);
    }

    const char* Kc = (const char*)&Ks[cur][0];
    const char* Vc = (const char*)&Vs[cur][0];

#pragma unroll
    for (int s = 0; s < 2; ++s) {
      const int qs0 = qw + s*16;              // first q-row of this set
      if (kv0 > qs0 + 15) continue;           // fully-masked set: skip
      const int qa = qs0 + fr;                // this lane's absolute q row

      // S^T = K Q^T : lane fr = q, regs hold kv = n*16 + fg*4 + r  (log2 domain)
      f32x4 sa[4];
      __builtin_amdgcn_s_setprio(1);
#pragma unroll
      for (int n = 0; n < 4; ++n) {
        const int row = n*16 + fr;
        const int sw = (row & 7) << 4;
        const half8 k0v = *(const half8*)(Kc + row*128 + ((fg*16) ^ sw));
        const half8 k1v = *(const half8*)(Kc + row*128 + ((64 + fg*16) ^ sw));
        f32x4 z = {0.f, 0.f, 0.f, 0.f};
        z = __builtin_amdgcn_mfma_f32_16x16x32_f16(k0v, qf[s][0], z, 0, 0, 0);
        sa[n] = __builtin_amdgcn_mfma_f32_16x16x32_f16(k1v, qf[s][1], z, 0, 0, 0);
      }
      __builtin_amdgcn_s_setprio(0);

      if (kv0 + 63 > qs0) {                   // masked region reaches this set
#pragma unroll
        for (int n = 0; n < 4; ++n) {
          const int kvb = kv0 + n*16 + fg*4;
#pragma unroll
          for (int r = 0; r < 4; ++r)
            if (kvb + r > qa) sa[n][r] = -1e30f;
        }
      }

      // row max: vector tree + 2 shuffles
      f32x4 mx = vmax4(vmax4(sa[0], sa[1]), vmax4(sa[2], sa[3]));
      float pm = fmaxf(fmaxf(mx[0], mx[1]), fmaxf(mx[2], mx[3]));
      pm = fmaxf(pm, __shfl_xor(pm, 16));
      pm = fmaxf(pm, __shfl_xor(pm, 32));

      // defer-max: skip rescale unless max grew by > 8 (log2 units)
      if (!__all(pm <= m_s[s] + 8.0f)) {
        const float mn = fmaxf(m_s[s], pm);
        const float fac = EXP2(m_s[s] - mn);
        m_s[s] = mn;
        l_s[s] *= fac;
#pragma unroll
        for (int n = 0; n < 4; ++n) oaccT[s][n] *= fac;
      }
      const float mrow = m_s[s];

#pragma unroll
      for (int n = 0; n < 4; ++n)
#pragma unroll
        for (int r = 0; r < 4; ++r)
          sa[n][r] = EXP2(sa[n][r] - mrow);

      f32x4 s4 = (sa[0] + sa[1]) + (sa[2] + sa[3]);
      float ps = (s4[0] + s4[1]) + (s4[2] + s4[3]);
      ps += __shfl_xor(ps, 16);
      ps += __shfl_xor(ps, 32);
      l_s[s] += ps;

      // P (row q=fr, kv-consecutive) -> packed cvt + b64 writes, XOR-swizzled
#pragma unroll
      for (int n = 0; n < 4; ++n) {
        half2v lo = (half2v)__builtin_amdgcn_cvt_pkrtz(sa[n][0], sa[n][1]);
        half2v hi = (half2v)__builtin_amdgcn_cvt_pkrtz(sa[n][2], sa[n][3]);
        half4 p4 = __builtin_shufflevector(lo, hi, 0, 1, 2, 3);
        *(half4*)(Pb + ((fr*128 + n*32 + fg*8) ^ swp)) = p4;
      }

      // O^T += V^T P^T : A = V^T frag (lane fr = d), B = P frag (lane fr = q)
      __builtin_amdgcn_s_setprio(1);
#pragma unroll
      for (int ks = 0; ks < 2; ++ks) {
        const half8 pf = *(const half8*)(Pb + ((fr*128 + ks*64 + fg*16) ^ swp));
#pragma unroll
        for (int nd = 0; nd < 4; ++nd) {
          const int row = nd*16 + fr;
          const int sw = (row & 7) << 4;
          const half8 vf = *(const half8*)(Vc + row*128 + ((ks*64 + fg*16) ^ sw));
          oaccT[s][nd] = __builtin_amdgcn_mfma_f32_16x16x32_f16(vf, pf, oaccT[s][nd], 0, 0, 0);
        }
      }
      __builtin_amdgcn_s_setprio(0);
    }

    __syncthreads();           // implicit vmcnt(0): prefetch drained; buffers swappable
    cur ^= 1;
  }

  // epilogue: O^T lane fr = q -> row-contiguous packed stores
#pragma unroll
  for (int s = 0; s < 2; ++s) {
    const float rl = __builtin_amdgcn_rcpf(l_s[s]);
    _Float16* orow = O + ((long)b*SEQ + (qw + s*16 + fr))*DM + h*64;
#pragma unroll
    for (int nd = 0; nd < 4; ++nd) {
      half2v lo = (half2v)__builtin_amdgcn_cvt_pkrtz(oaccT[s][nd][0]*rl, oaccT[s][nd][1]*rl);
      half2v hi = (half2v)__builtin_amdgcn_cvt_pkrtz(oaccT[s][nd][2]*rl, oaccT[s][nd][3]*rl);
      half4 o4 = __builtin_shufflevector(lo, hi, 0, 1, 2, 3);
      *(half4*)&orow[nd*16 + fg*4] = o4;
    }
  }
}

extern "C" void kernel_launch(void* const* d_in, const int* in_sizes, int n_in,
                              void* d_out, int out_size, void* d_ws, size_t ws_size,
                              hipStream_t stream) {
  const float* x  = (const float*)d_in[0];
  const float* Wq = (const float*)d_in[1];
  const float* Wk = (const float*)d_in[2];
  const float* Wv = (const float*)d_in[3];
  const float* Wo = (const float*)d_in[4];
  const int*   tp = (const int*)d_in[5];
  float* out = (float*)d_out;

  char* ws = (char*)d_ws;
  _Float16* xh   = (_Float16*)(ws);                  // 16 MB  [8192][1024]
  _Float16* Wqkv = (_Float16*)(ws + (16u << 20));    //  6 MB  [3072][1024]
  _Float16* Woh  = (_Float16*)(ws + (22u << 20));    //  2 MB  [1024][1024]
  _Float16* Qb   = (_Float16*)(ws + (24u << 20));    // 16 MB  [64][2048][64]
  _Float16* Kb   = (_Float16*)(ws + (40u << 20));    // 16 MB
  _Float16* Vtb  = (_Float16*)(ws + (56u << 20));    // 16 MB  [64][64][2048]
  _Float16* attn = (_Float16*)(ws + (72u << 20));    // 16 MB  [8192][1024]

  cvt4<<<8192, 256, 0, stream>>>(x,  xh, 2097152);
  cvt4<<<1024, 256, 0, stream>>>(Wq, Wqkv,               262144);
  cvt4<<<1024, 256, 0, stream>>>(Wk, Wqkv + (1u << 20),  262144);
  cvt4<<<1024, 256, 0, stream>>>(Wv, Wqkv + (2u << 20),  262144);
  cvt4<<<1024, 256, 0, stream>>>(Wo, Woh,                262144);

  gemm_hk<0><<<dim3(64, 24), 256, 0, stream>>>(xh, Wqkv, Qb, Kb, Vtb, nullptr);
  rope_k<<<dim3(256, 64, 2), 256, 0, stream>>>(Qb, Kb, tp);
  fattn<<<dim3(64, 16), 256, 0, stream>>>(Qb, Kb, Vtb, attn);
  gemm_hk<1><<<dim3(64, 8), 256, 0, stream>>>(attn, Woh, nullptr, nullptr, nullptr, out);
}

// Round 6
// 195.081 us; speedup vs baseline: 1.1237x; 1.0174x over previous
//
#include <hip/hip_runtime.h>
#include <hip/hip_fp16.h>

typedef _Float16 half8 __attribute__((ext_vector_type(8)));
typedef _Float16 half4 __attribute__((ext_vector_type(4)));
typedef _Float16 half2v __attribute__((ext_vector_type(2)));
typedef float f32x4 __attribute__((ext_vector_type(4)));

#define SEQ   2048
#define DM    1024
#define NH    16
#define HD    64
#define BSZ   4

#if __has_builtin(__builtin_amdgcn_exp2f)
#define EXP2(x) __builtin_amdgcn_exp2f(x)
#else
#define EXP2(x) exp2f(x)
#endif

// Q pre-scale: (1/sqrt(64)) * log2(e)  -> scores land in log2 domain
#define QSCALE 0.1803368801f

// async global->LDS, 16B per lane. LDS dest = wave-uniform base + lane*16.
__device__ __forceinline__ void gload16(const void* g, void* l) {
  __builtin_amdgcn_global_load_lds((const __attribute__((address_space(1))) void*)g,
                                   (__attribute__((address_space(3))) void*)l,
                                   16, 0, 0);
}

__device__ __forceinline__ f32x4 vmax4(f32x4 a, f32x4 b) {
  f32x4 r;
  r[0] = fmaxf(a[0], b[0]); r[1] = fmaxf(a[1], b[1]);
  r[2] = fmaxf(a[2], b[2]); r[3] = fmaxf(a[3], b[3]);
  return r;
}

// ---------------- fp32 -> fp16 convert (vectorized) ----------------
__global__ void cvt4(const float* __restrict__ src, _Float16* __restrict__ dst, int n4) {
  int i = blockIdx.x * blockDim.x + threadIdx.x;
  if (i < n4) {
    float4 v = ((const float4*)src)[i];
    half4 o = { (_Float16)v.x, (_Float16)v.y, (_Float16)v.z, (_Float16)v.w };
    ((half4*)dst)[i] = o;
  }
}

// ---------------- GEMM: C = A * B^T, A[M][1024] f16, B[N][1024] f16 ----------------
// 128x128 tile, 4 waves (2x2), BK=32, 16x16x32 f16 MFMA (m97 structure).
// MODE 0: QKV projection epilogue -> Q(scaled by QSCALE)[bh][s][64], K[bh][s][64],
//         Vt[bh][64][s] (f16)
// MODE 1: plain f32 store to out[M][1024]
template<int MODE>
__global__ __launch_bounds__(256)
void gemm_hk(const _Float16* __restrict__ A, const _Float16* __restrict__ B,
             _Float16* __restrict__ oQ, _Float16* __restrict__ oK,
             _Float16* __restrict__ oVt, float* __restrict__ oF) {
  __shared__ _Float16 As[128*32];
  __shared__ _Float16 Bs[128*32];
  const int tid  = threadIdx.x;
  const int wid  = tid >> 6, lane = tid & 63;
  const int wm   = wid >> 1, wn = wid & 1;
  const int fr   = lane & 15, fg = lane >> 4;
  const long m0  = (long)blockIdx.x * 128;
  const long n0  = (long)blockIdx.y * 128;
  const int lrow = lane >> 2;            // 16 rows per instr (4 lanes/row)
  const int lcol = (lane & 3) * 8;       // halfs
  const _Float16* ga0 = A + (m0 + wid*32 + lrow) * 1024 + lcol;
  const _Float16* gb0 = B + (n0 + wid*32 + lrow) * 1024 + lcol;
  _Float16* lA = &As[wid*32*32];
  _Float16* lB = &Bs[wid*32*32];

  f32x4 acc[4][4] = {};

  for (int k0 = 0; k0 < 1024; k0 += 32) {
    gload16(ga0 + k0,             lA);
    gload16(ga0 + k0 + 16*1024,   lA + 16*32);
    gload16(gb0 + k0,             lB);
    gload16(gb0 + k0 + 16*1024,   lB + 16*32);
    __syncthreads();
    half8 af[4], bf[4];
#pragma unroll
    for (int i = 0; i < 4; ++i) {
      af[i] = *(const half8*)&As[(wm*64 + i*16 + fr)*32 + fg*8];
      bf[i] = *(const half8*)&Bs[(wn*64 + i*16 + fr)*32 + fg*8];
    }
#pragma unroll
    for (int i = 0; i < 4; ++i)
#pragma unroll
      for (int j = 0; j < 4; ++j)
        acc[i][j] = __builtin_amdgcn_mfma_f32_16x16x32_f16(af[i], bf[j], acc[i][j], 0, 0, 0);
    __syncthreads();
  }

  if (MODE == 0) {
    const int which = (int)(n0 >> 10);               // 0=Q 1=K 2=V (tiles never straddle)
    const int nloc0 = ((int)n0 & 1023) + wn*64;
#pragma unroll
    for (int i = 0; i < 4; ++i) {
      const long r0 = m0 + wm*64 + i*16 + fg*4;
      const int  bb = (int)(r0 >> 11);
      const int  s  = (int)(r0 & 2047);
#pragma unroll
      for (int j = 0; j < 4; ++j) {
        const int nl = nloc0 + j*16 + fr;
        const int h  = nl >> 6, d = nl & 63;
        const long bh = (long)(bb*NH + h);
        if (which == 0) {
#pragma unroll
          for (int r = 0; r < 4; ++r)
            oQ[(bh*SEQ + s + r)*HD + d] = (_Float16)(acc[i][j][r] * QSCALE);
        } else if (which == 1) {
#pragma unroll
          for (int r = 0; r < 4; ++r)
            oK[(bh*SEQ + s + r)*HD + d] = (_Float16)acc[i][j][r];
        } else {
          half4 pk = { (_Float16)acc[i][j][0], (_Float16)acc[i][j][1],
                       (_Float16)acc[i][j][2], (_Float16)acc[i][j][3] };
          *(half4*)&oVt[(bh*HD + d)*SEQ + s] = pk;   // s % 4 == 0, 8B aligned
        }
      }
    }
  } else {
#pragma unroll
    for (int i = 0; i < 4; ++i) {
      const long r0 = m0 + wm*64 + i*16 + fg*4;
#pragma unroll
      for (int j = 0; j < 4; ++j) {
        const long col = n0 + wn*64 + j*16 + fr;
#pragma unroll
        for (int r = 0; r < 4; ++r)
          oF[(r0 + r)*DM + col] = acc[i][j][r];
      }
    }
  }
}

// ---------------- RoPE in place on Q and K [bh][s][64] ----------------
__global__ void rope_k(_Float16* __restrict__ Q, _Float16* __restrict__ K,
                       const int* __restrict__ tp) {
  const int t = blockIdx.x * blockDim.x + threadIdx.x;   // over SEQ*32
  const int s = t >> 5, p = t & 31;
  _Float16* base = blockIdx.z ? K : Q;
  half2v* ptr = (half2v*)(base + ((long)blockIdx.y * SEQ + s) * HD) + p;
  half2v v = *ptr;
  const float pos = (float)tp[s];
  const float inv = exp2f(-0.41524101186f * (float)p);
  const float f = pos * inv;
  float sn, cs;
  __sincosf(f, &sn, &cs);
  const float xe = (float)v[0], xo = (float)v[1];
  half2v o = { (_Float16)(xe*cs - xo*sn), (_Float16)(xo*cs + xe*sn) };
  *ptr = o;
}

// ---------------- causal flash attention (swapped-operand, log2-domain, paired) ------
// grid (BH=64, 16). EQUAL-WEIGHT blocks: each wave's two 16-row q-sets come from
// COMPLEMENTARY q-tiles — set0 from heavy tile (31-y), set1 from light tile y
// (64-row tiles). Per-wave compute = (32-y)+(y+1) = 33 set-units, constant across
// all 1024 blocks -> 4 equal blocks/CU co-resident, no occupancy decay tail
// (round-5 counter: 28% occupancy = per-CU wave decay as light blocks finished).
// S^T = mfma(K,Q): lane fr = q -> row stats LANE-LOCAL. O^T = mfma(V,P).
// Scores in log2 domain -> exp2 direct. Defer-max THR=8. K-frags read inline
// (no hoist: spill, round-3 lesson). P via cvt_pkrtz into XOR-swizzled per-wave
// LDS. LDS = 40960 B -> 4 blocks/CU.
__global__ __launch_bounds__(256, 4)
void fattn(const _Float16* __restrict__ Q, const _Float16* __restrict__ K,
           const _Float16* __restrict__ Vt, _Float16* __restrict__ O) {
  __shared__ _Float16 Ks[2][64*64];
  __shared__ _Float16 Vs[2][64*64];
  __shared__ _Float16 Ps[4][16*64];      // per-wave, XOR-swizzled, stride 64
  const int tid = threadIdx.x, wid = tid >> 6, lane = tid & 63;
  const int fr = lane & 15, fg = lane >> 4;
  const int bh = blockIdx.x;
  const int b = bh >> 4, h = bh & 15;
  const int y = blockIdx.y;              // 0..15
  const int q0H = (31 - y) * 64;         // heavy 64-row q-tile
  const int q0L = y * 64;                // light 64-row q-tile
  const int qs_[2] = { q0H + wid*16, q0L + wid*16 };   // set -> first q-row
  const _Float16* Qb = Q + (long)bh * SEQ * HD;
  const _Float16* Kb = K + (long)bh * SEQ * HD;
  const _Float16* Vb = Vt + (long)bh * HD * SEQ;

  half8 qf[2][2];
#pragma unroll
  for (int s = 0; s < 2; ++s) {
    qf[s][0] = *(const half8*)&Qb[(qs_[s] + fr)*HD + fg*8];
    qf[s][1] = *(const half8*)&Qb[(qs_[s] + fr)*HD + 32 + fg*8];
  }

  f32x4 oaccT[2][4] = {};
  float m_s[2] = { -1e30f, -1e30f }, l_s[2] = { 0.f, 0.f };

  const int srow = lane >> 3;                 // 0..7 (row within 8-row chunk)
  const int sc16 = (lane & 7) ^ srow;         // pre-swizzled source slot
  const int r1 = wid*16 + srow, r2 = r1 + 8;  // rows this wave stages

  char* Pb = (char*)&Ps[wid][0];
  const int swp = (fr & 7) << 4;              // P swizzle for this lane's q-row
  const int nt = (q0H >> 6) + 1;              // 32 - y kv-tiles

  // prologue: stage tile 0 into buf 0
  gload16(Kb + (long)r1*HD + sc16*8, &Ks[0][(wid*16)*64]);
  gload16(Kb + (long)r2*HD + sc16*8, &Ks[0][(wid*16 + 8)*64]);
  gload16(Vb + (long)r1*SEQ + sc16*8, &Vs[0][(wid*16)*64]);
  gload16(Vb + (long)r2*SEQ + sc16*8, &Vs[0][(wid*16 + 8)*64]);
  __syncthreads();

  int cur = 0;
  for (int t = 0; t < nt; ++t) {
    const int kv0 = t * 64;

    // prefetch next tile (drained by end-of-tile barrier -> latency hidden)
    if (t + 1 < nt) {
      const int nkv = kv0 + 64;
      gload16(Kb + (long)(nkv + r1)*HD + sc16*8, &Ks[cur^1][(wid*16)*64]);
      gload16(Kb + (long)(nkv + r2)*HD + sc16*8, &Ks[cur^1][(wid*16 + 8)*64]);
      gload16(Vb + (long)r1*SEQ + nkv + sc16*8,  &Vs[cur^1][(wid*16)*64]);
      gload16(Vb + (long)r2*SEQ + nkv + sc16*8,  &Vs[cur^1][(wid*16 + 8)*64]);
    }

    const char* Kc = (const char*)&Ks[cur][0];
    const char* Vc = (const char*)&Vs[cur][0];

#pragma unroll
    for (int s = 0; s < 2; ++s) {
      const int qs0 = qs_[s];                 // first q-row of this set
      if (kv0 > qs0 + 15) continue;           // fully-masked set: skip
      const int qa = qs0 + fr;                // this lane's absolute q row

      // S^T = K Q^T : lane fr = q, regs hold kv = n*16 + fg*4 + r  (log2 domain)
      f32x4 sa[4];
      __builtin_amdgcn_s_setprio(1);
#pragma unroll
      for (int n = 0; n < 4; ++n) {
        const int row = n*16 + fr;
        const int sw = (row & 7) << 4;
        const half8 k0v = *(const half8*)(Kc + row*128 + ((fg*16) ^ sw));
        const half8 k1v = *(const half8*)(Kc + row*128 + ((64 + fg*16) ^ sw));
        f32x4 z = {0.f, 0.f, 0.f, 0.f};
        z = __builtin_amdgcn_mfma_f32_16x16x32_f16(k0v, qf[s][0], z, 0, 0, 0);
        sa[n] = __builtin_amdgcn_mfma_f32_16x16x32_f16(k1v, qf[s][1], z, 0, 0, 0);
      }
      __builtin_amdgcn_s_setprio(0);

      if (kv0 + 63 > qs0) {                   // masked region reaches this set
#pragma unroll
        for (int n = 0; n < 4; ++n) {
          const int kvb = kv0 + n*16 + fg*4;
#pragma unroll
          for (int r = 0; r < 4; ++r)
            if (kvb + r > qa) sa[n][r] = -1e30f;
        }
      }

      // row max: vector tree + 2 shuffles
      f32x4 mx = vmax4(vmax4(sa[0], sa[1]), vmax4(sa[2], sa[3]));
      float pm = fmaxf(fmaxf(mx[0], mx[1]), fmaxf(mx[2], mx[3]));
      pm = fmaxf(pm, __shfl_xor(pm, 16));
      pm = fmaxf(pm, __shfl_xor(pm, 32));

      // defer-max: skip rescale unless max grew by > 8 (log2 units)
      if (!__all(pm <= m_s[s] + 8.0f)) {
        const float mn = fmaxf(m_s[s], pm);
        const float fac = EXP2(m_s[s] - mn);
        m_s[s] = mn;
        l_s[s] *= fac;
#pragma unroll
        for (int n = 0; n < 4; ++n) oaccT[s][n] *= fac;
      }
      const float mrow = m_s[s];

#pragma unroll
      for (int n = 0; n < 4; ++n)
#pragma unroll
        for (int r = 0; r < 4; ++r)
          sa[n][r] = EXP2(sa[n][r] - mrow);

      f32x4 s4 = (sa[0] + sa[1]) + (sa[2] + sa[3]);
      float ps = (s4[0] + s4[1]) + (s4[2] + s4[3]);
      ps += __shfl_xor(ps, 16);
      ps += __shfl_xor(ps, 32);
      l_s[s] += ps;

      // P (row q=fr, kv-consecutive) -> packed cvt + b64 writes, XOR-swizzled
#pragma unroll
      for (int n = 0; n < 4; ++n) {
        half2v lo = (half2v)__builtin_amdgcn_cvt_pkrtz(sa[n][0], sa[n][1]);
        half2v hi = (half2v)__builtin_amdgcn_cvt_pkrtz(sa[n][2], sa[n][3]);
        half4 p4 = __builtin_shufflevector(lo, hi, 0, 1, 2, 3);
        *(half4*)(Pb + ((fr*128 + n*32 + fg*8) ^ swp)) = p4;
      }

      // O^T += V^T P^T : A = V^T frag (lane fr = d), B = P frag (lane fr = q)
      __builtin_amdgcn_s_setprio(1);
#pragma unroll
      for (int ks = 0; ks < 2; ++ks) {
        const half8 pf = *(const half8*)(Pb + ((fr*128 + ks*64 + fg*16) ^ swp));
#pragma unroll
        for (int nd = 0; nd < 4; ++nd) {
          const int row = nd*16 + fr;
          const int sw = (row & 7) << 4;
          const half8 vf = *(const half8*)(Vc + row*128 + ((ks*64 + fg*16) ^ sw));
          oaccT[s][nd] = __builtin_amdgcn_mfma_f32_16x16x32_f16(vf, pf, oaccT[s][nd], 0, 0, 0);
        }
      }
      __builtin_amdgcn_s_setprio(0);
    }

    __syncthreads();           // implicit vmcnt(0): prefetch drained; buffers swappable
    cur ^= 1;
  }

  // epilogue: O^T lane fr = q -> row-contiguous packed stores
#pragma unroll
  for (int s = 0; s < 2; ++s) {
    const float rl = __builtin_amdgcn_rcpf(l_s[s]);
    _Float16* orow = O + ((long)b*SEQ + (qs_[s] + fr))*DM + h*64;
#pragma unroll
    for (int nd = 0; nd < 4; ++nd) {
      half2v lo = (half2v)__builtin_amdgcn_cvt_pkrtz(oaccT[s][nd][0]*rl, oaccT[s][nd][1]*rl);
      half2v hi = (half2v)__builtin_amdgcn_cvt_pkrtz(oaccT[s][nd][2]*rl, oaccT[s][nd][3]*rl);
      half4 o4 = __builtin_shufflevector(lo, hi, 0, 1, 2, 3);
      *(half4*)&orow[nd*16 + fg*4] = o4;
    }
  }
}

extern "C" void kernel_launch(void* const* d_in, const int* in_sizes, int n_in,
                              void* d_out, int out_size, void* d_ws, size_t ws_size,
                              hipStream_t stream) {
  const float* x  = (const float*)d_in[0];
  const float* Wq = (const float*)d_in[1];
  const float* Wk = (const float*)d_in[2];
  const float* Wv = (const float*)d_in[3];
  const float* Wo = (const float*)d_in[4];
  const int*   tp = (const int*)d_in[5];
  float* out = (float*)d_out;

  char* ws = (char*)d_ws;
  _Float16* xh   = (_Float16*)(ws);                  // 16 MB  [8192][1024]
  _Float16* Wqkv = (_Float16*)(ws + (16u << 20));    //  6 MB  [3072][1024]
  _Float16* Woh  = (_Float16*)(ws + (22u << 20));    //  2 MB  [1024][1024]
  _Float16* Qb   = (_Float16*)(ws + (24u << 20));    // 16 MB  [64][2048][64]
  _Float16* Kb   = (_Float16*)(ws + (40u << 20));    // 16 MB
  _Float16* Vtb  = (_Float16*)(ws + (56u << 20));    // 16 MB  [64][64][2048]
  _Float16* attn = (_Float16*)(ws + (72u << 20));    // 16 MB  [8192][1024]

  cvt4<<<8192, 256, 0, stream>>>(x,  xh, 2097152);
  cvt4<<<1024, 256, 0, stream>>>(Wq, Wqkv,               262144);
  cvt4<<<1024, 256, 0, stream>>>(Wk, Wqkv + (1u << 20),  262144);
  cvt4<<<1024, 256, 0, stream>>>(Wv, Wqkv + (2u << 20),  262144);
  cvt4<<<1024, 256, 0, stream>>>(Wo, Woh,                262144);

  gemm_hk<0><<<dim3(64, 24), 256, 0, stream>>>(xh, Wqkv, Qb, Kb, Vtb, nullptr);
  rope_k<<<dim3(256, 64, 2), 256, 0, stream>>>(Qb, Kb, tp);
  fattn<<<dim3(64, 16), 256, 0, stream>>>(Qb, Kb, Vtb, attn);
  gemm_hk<1><<<dim3(64, 8), 256, 0, stream>>>(attn, Woh, nullptr, nullptr, nullptr, out);
}